// Round 2
// baseline (187.115 us; speedup 1.0000x reference)
//
#include <hip/hip_runtime.h>
#include <hip/hip_bf16.h>
#include <cstdint>
#include <cstddef>

#define B_DIM 256
#define T_DIM 256
#define EMB   384
#define HEAD  64

typedef __attribute__((ext_vector_type(8))) short bf16x8;
typedef __attribute__((ext_vector_type(4))) float f32x4;
typedef __attribute__((ext_vector_type(4))) unsigned int u32x4;

__device__ __forceinline__ unsigned short f2bf(float f) {
    union { float f; unsigned int u; } v; v.f = f;
    unsigned int r = v.u + 0x7fffu + ((v.u >> 16) & 1u);  // RNE
    return (unsigned short)(r >> 16);
}

__device__ __forceinline__ unsigned int pkbf(float a, float b) {
#if __has_builtin(__builtin_amdgcn_cvt_pk_bf16_f32)
    typedef __attribute__((ext_vector_type(2))) __bf16 bf16x2_t;
    bf16x2_t r = __builtin_amdgcn_cvt_pk_bf16_f32(a, b);
    return *(unsigned int*)&r;
#else
    return (unsigned)f2bf(a) | ((unsigned)f2bf(b) << 16);
#endif
}

// ---------------------------------------------------------------------------
// Kernel 0: W prep — Wq|Wk|Wv fp32 [384][64] -> Wb bf16, chunk-permuted for
// global_load_lds staging. Chunk g = kkstep*1536 + r*8 + cs holds the 8
// k-values of source chunk c = cs ^ (r&7) of output-col r in k-step kkstep.
// Makes the unpadded LDS image conflict-free for swizzled B-frag reads.
// ---------------------------------------------------------------------------
__global__ void wprep_kernel(const float* __restrict__ Wq, const float* __restrict__ Wk,
                             const float* __restrict__ Wv, unsigned short* __restrict__ Wb) {
    int g = blockIdx.x * blockDim.x + threadIdx.x;
    if (g >= 9216) return;                 // 6 k-steps * 1536 chunks
    int kkstep = g / 1536, rem = g - kkstep * 1536;
    int r = rem >> 3, cs = rem & 7, c = cs ^ (r & 7);
    const float* W = (r < 64) ? Wq : (r < 128) ? Wk : Wv;
    int h = r & 63;
    unsigned short tmp[8];
#pragma unroll
    for (int e = 0; e < 8; ++e) {
        int k = kkstep * 64 + c * 8 + e;
        tmp[e] = f2bf(W[k * HEAD + h]);
    }
    *(u32x4*)(Wb + (size_t)g * 8) = *(u32x4*)tmp;
}

// ---------------------------------------------------------------------------
// Fused kernel: one block per batch, 512 threads (8 waves), 1 block/CU.
//
// v3 change (register-cap fix): v2's x-stash needed a ~220-VGPR live set but
// __launch_bounds__(512, 2) was translated as 2 BLOCKS/CU -> 4 waves/EU ->
// VGPR cap 128 (observed VGPR_Count=128): the stash AND part of acc spilled
// to scratch, making the k-loop scratch-latency-bound (MfmaUtil 5%, 85 us).
// Now __launch_bounds__(512, 1): 8 waves/CU -> 2 waves/EU -> cap 256. Also
// slices 0/1 are scattered to LDS immediately after conversion (st0 dies
// before st1/st2 are built), trimming prologue peak pressure.
//
// x-stash (from v2): a PROLOGUE streams the block's whole 393 KB x-slice
// once, address-ascending, into a register-resident bf16 stash (thread t
// owns row r=t>>1, half h=t&1, k-slices {h, 2+h, 4+h}; 48 float4 loads ->
// 96 u32 bf16, 3-chunk-deep load/convert pipeline). This replaces v1's 6
// per-k-step column-slice passes (256 B used per 1536 B row per pass ->
// ~40% DRAM page efficiency). The k-loop is LDS/MFMA-only: slice kk+1 is
// scattered stash->Xs (8x ds_write_b128 by half the threads) into the
// buffer NOT being read this step, so the single __syncthreads per k-step
// still covers all hazards. Xs image, Ws glds path, MFMA code and phase 2
// are identical to v1 -> numerics unchanged.
//
// Phase 1: QKV GEMM M=256(tok) x N=192(ch), K=384. Wave (mh,nh) = 64 rows x
//   96 cols, acc[4][6]. ONE barrier per k-step; W via global_load_lds(16B)
//   double-buffered, drained by the next barrier's vmcnt(0).
// Phase 2: acc scatters q/k/vT straight to LDS (vT packed b64); attention
//   runs fully in LDS. Wave w owns row-tiles {w, 15-w}: 17 col-tiles and 5
//   PV chunks per wave — perfectly balanced causal triangle.
// ---------------------------------------------------------------------------
__global__ __launch_bounds__(512, 1) void fused_kernel(const float* __restrict__ x,
                                                       const unsigned short* __restrict__ Wb,
                                                       float* __restrict__ out) {
    __shared__ union SM {
        struct { unsigned short Xs[2][256][72]; unsigned short Ws[2][12288]; } p1;  // 122,880 B
        struct { unsigned short qs[256][72]; unsigned short ks[256][72];
                 unsigned short vT[64][264]; unsigned short Ps[8][16][72]; } p2;    // 125,952 B
    } sm;

    const int tid = threadIdx.x;
    const int w = tid >> 6, lane = tid & 63, qd = lane >> 4, l15 = lane & 15;
    const int mh = w >> 1, nh = w & 1;
    const int b = blockIdx.x;
    const float* xb = x + (size_t)b * T_DIM * EMB;
    const int r = tid >> 1, h = tid & 1;          // x-stash coords: row, col-half parity

    // ---- W(0) glds first (L2-resident; overlaps the x stream) ----
#pragma unroll
    for (int s = 0; s < 3; ++s) {
        int idx = s * 512 + w * 64;  // wave-uniform base
        const unsigned short* gp = Wb + (size_t)(idx + lane) * 8;
        unsigned short* lp = &sm.p1.Ws[0][idx * 8];
        __builtin_amdgcn_global_load_lds(
            (const __attribute__((address_space(1))) unsigned int*)gp,
            (__attribute__((address_space(3))) unsigned int*)lp, 16, 0, 0);
    }

    // ---- x prologue: stream 768 B/thread once, convert to bf16 stash ----
    // thread (r,h) owns k-slices kk = 2j+h (j=0..2): float cols j*128+h*64..+64
    // chunk c = (j = c>>1, half = c&1): 8 float4 = 128 B; 3 chunks in flight
    // keeps ~768 B/row outstanding -> good DRAM page coverage.
    const float* xp = xb + (size_t)r * EMB + h * 64;
    float4 xf[3][8];
    unsigned int st0[32], st1[32], st2[32];       // bf16x2 stash, slice j=0/1/2

#define LOADC(BUF, C) do { \
    _Pragma("unroll") \
    for (int ii = 0; ii < 8; ++ii) \
        xf[BUF][ii] = *(const float4*)(xp + ((C) >> 1) * 128 + ((C) & 1) * 32 + ii * 4); \
} while (0)

#define CONVC(BUF, ST, C) do { \
    _Pragma("unroll") \
    for (int ii = 0; ii < 8; ++ii) { \
        ST[16 * ((C) & 1) + 2 * ii]     = pkbf(xf[BUF][ii].x, xf[BUF][ii].y); \
        ST[16 * ((C) & 1) + 2 * ii + 1] = pkbf(xf[BUF][ii].z, xf[BUF][ii].w); \
    } \
} while (0)

    // scatter slice S (k-step S) to Xs[S&1]; active threads h == S&1 write
    // their full 64-short row slice as 8x ds_write_b128 (4-way bank alias,
    // ~free). Xs image identical to v1's staging.
#define SCATTER(ST, S) do { \
    if (h == ((S) & 1)) { \
        _Pragma("unroll") \
        for (int q = 0; q < 8; ++q) \
            *(u32x4*)&sm.p1.Xs[(S) & 1][r][8 * q] = \
                (u32x4){ST[4 * q], ST[4 * q + 1], ST[4 * q + 2], ST[4 * q + 3]}; \
    } \
} while (0)

    LOADC(0, 0); LOADC(1, 1); LOADC(2, 2);
    CONVC(0, st0, 0); LOADC(0, 3);
    CONVC(1, st0, 1); LOADC(1, 4);
    // slices 0 and 1 go straight to LDS (st0 dies before st1/st2 are built)
    SCATTER(st0, 0);
    SCATTER(st0, 1);
    CONVC(2, st1, 2); LOADC(2, 5);
    CONVC(0, st1, 3);
    CONVC(1, st2, 4);
    CONVC(2, st2, 5);

    f32x4 acc[4][6];
#pragma unroll
    for (int mt = 0; mt < 4; ++mt)
#pragma unroll
        for (int nt = 0; nt < 6; ++nt) acc[mt][nt] = (f32x4){0.f, 0.f, 0.f, 0.f};

    // ---- main K loop: LDS/MFMA only; one barrier per step ----
    // step kk reads Xs[kk&1]/Ws[kk&1]; issues glds Ws[(kk+1)&1] (drained by
    // NEXT barrier's vmcnt(0) -> one full step of overlap); scatters slice
    // kk+1 into Xs[(kk+1)&1] (buffer not read this step; readers are behind
    // the next barrier; previous occupant slice kk-1 was fully read before
    // THIS barrier). Fully unrolled so stash indexing stays compile-time.
#pragma unroll
    for (int kk = 0; kk < 6; ++kk) {
        __syncthreads();   // drains prev glds (vmcnt) + scatter/frag LDS ops (lgkm)
        if (kk < 5) {
#pragma unroll
            for (int s = 0; s < 3; ++s) {
                int idx = s * 512 + w * 64;
                const unsigned short* gp = Wb + (size_t)((kk + 1) * 1536 + idx + lane) * 8;
                unsigned short* lp = &sm.p1.Ws[(kk + 1) & 1][idx * 8];
                __builtin_amdgcn_global_load_lds(
                    (const __attribute__((address_space(1))) unsigned int*)gp,
                    (__attribute__((address_space(3))) unsigned int*)lp, 16, 0, 0);
            }
        }
#pragma unroll
        for (int kb = 0; kb < 2; ++kb) {
            bf16x8 a[4], bb[6];
#pragma unroll
            for (int mt = 0; mt < 4; ++mt)
                a[mt] = *(const bf16x8*)&sm.p1.Xs[kk & 1][64 * mh + 16 * mt + l15][32 * kb + 8 * qd];
#pragma unroll
            for (int nt = 0; nt < 6; ++nt) {
                int n = 96 * nh + 16 * nt + l15;
                bb[nt] = *(const bf16x8*)&sm.p1.Ws[kk & 1][n * 64 + (((4 * kb + qd) ^ (n & 7)) << 3)];
            }
#pragma unroll
            for (int mt = 0; mt < 4; ++mt)
#pragma unroll
                for (int nt = 0; nt < 6; ++nt)
                    acc[mt][nt] = __builtin_amdgcn_mfma_f32_16x16x32_bf16(a[mt], bb[nt], acc[mt][nt], 0, 0, 0);
        }
        if (kk == 1) SCATTER(st1, 2);
        if (kk == 2) SCATTER(st1, 3);
        if (kk == 3) SCATTER(st2, 4);
        if (kk == 4) SCATTER(st2, 5);
    }
    __syncthreads();       // all GEMM LDS reads done; safe to repurpose union

    // scatter acc -> qs / ks / vT  (C/D layout: col=l15(ch), row=4*qd+reg(tok))
#pragma unroll
    for (int nt = 0; nt < 6; ++nt) {
        int n = 96 * nh + 16 * nt + l15;
        int arr = n >> 6, hh = n & 63;         // arr is wave-uniform per nt
        if (arr == 2) {                        // vT: token-contiguous -> packed b64
#pragma unroll
            for (int mt = 0; mt < 4; ++mt) {
                int tok0 = 64 * mh + 16 * mt + 4 * qd;
                *(uint2*)&sm.p2.vT[hh][tok0] = make_uint2(
                    pkbf(acc[mt][nt][0], acc[mt][nt][1]),
                    pkbf(acc[mt][nt][2], acc[mt][nt][3]));
            }
        } else {
#pragma unroll
            for (int mt = 0; mt < 4; ++mt)
#pragma unroll
                for (int reg = 0; reg < 4; ++reg) {
                    int tok = 64 * mh + 16 * mt + 4 * qd + reg;
                    unsigned short val = f2bf(acc[mt][nt][reg]);
                    if (arr == 0) sm.p2.qs[tok][hh] = val;
                    else          sm.p2.ks[tok][hh] = val;
                }
        }
    }
    __syncthreads();       // q/k/vT ready

    // ---------------- attention, fully in LDS ----------------
    const int tiles[2] = { w, 15 - w };
    bf16x8 aq[2][2];
#pragma unroll
    for (int ti = 0; ti < 2; ++ti)
#pragma unroll
        for (int kbi = 0; kbi < 2; ++kbi)
            aq[ti][kbi] = *(const bf16x8*)&sm.p2.qs[16 * tiles[ti] + l15][32 * kbi + 8 * qd];

    f32x4 O[2][4];
    float l[2][4];
#pragma unroll
    for (int ti = 0; ti < 2; ++ti) {
#pragma unroll
        for (int dn = 0; dn < 4; ++dn) O[ti][dn] = (f32x4){0.f, 0.f, 0.f, 0.f};
#pragma unroll
        for (int reg = 0; reg < 4; ++reg) l[ti][reg] = 0.f;
    }

    const float cExp = 1.4426950408889634f / 19.595917942265423f; // log2(e)/sqrt(384)

#pragma unroll
    for (int ti = 0; ti < 2; ++ti) {
        const int t = tiles[ti];
        for (int jc = 0; jc <= (t >> 2); ++jc) {
            const int ntmax = min(3, t - 4 * jc);
            f32x4 S[4];
#pragma unroll
            for (int nt = 0; nt < 4; ++nt) {
                if (nt <= ntmax) {
                    bf16x8 b0 = *(const bf16x8*)&sm.p2.ks[64 * jc + 16 * nt + l15][8 * qd];
                    bf16x8 b1 = *(const bf16x8*)&sm.p2.ks[64 * jc + 16 * nt + l15][32 + 8 * qd];
                    f32x4 s = __builtin_amdgcn_mfma_f32_16x16x32_bf16(aq[ti][0], b0, (f32x4){0.f,0.f,0.f,0.f}, 0, 0, 0);
                    s = __builtin_amdgcn_mfma_f32_16x16x32_bf16(aq[ti][1], b1, s, 0, 0, 0);
                    S[nt] = s;
                }
            }
#pragma unroll
            for (int nt = 0; nt < 4; ++nt) {
#pragma unroll
                for (int reg = 0; reg < 4; ++reg) {
                    float p = 0.0f;
                    if (nt <= ntmax) {
                        p = exp2f(S[nt][reg] * cExp);
                        if (4 * jc + nt == t && (l15 > 4 * qd + reg)) p = 0.0f;  // diagonal mask
                    }
                    l[ti][reg] += p;
                    sm.p2.Ps[w][4 * qd + reg][16 * nt + l15] = f2bf(p);
                }
            }
            // C-layout -> A-layout via wave-private strip (no barrier needed)
            bf16x8 ap0 = *(const bf16x8*)&sm.p2.Ps[w][l15][8 * qd];
            bf16x8 ap1 = *(const bf16x8*)&sm.p2.Ps[w][l15][32 + 8 * qd];
#pragma unroll
            for (int dn = 0; dn < 4; ++dn) {
                bf16x8 bv0 = *(const bf16x8*)&sm.p2.vT[16 * dn + l15][64 * jc + 8 * qd];
                bf16x8 bv1 = *(const bf16x8*)&sm.p2.vT[16 * dn + l15][64 * jc + 32 + 8 * qd];
                O[ti][dn] = __builtin_amdgcn_mfma_f32_16x16x32_bf16(ap0, bv0, O[ti][dn], 0, 0, 0);
                O[ti][dn] = __builtin_amdgcn_mfma_f32_16x16x32_bf16(ap1, bv1, O[ti][dn], 0, 0, 0);
            }
        }
    }

#pragma unroll
    for (int ti = 0; ti < 2; ++ti) {
#pragma unroll
        for (int reg = 0; reg < 4; ++reg) {
            float s = l[ti][reg];
            s += __shfl_xor(s, 1);
            s += __shfl_xor(s, 2);
            s += __shfl_xor(s, 4);
            s += __shfl_xor(s, 8);
            float inv = 1.0f / s;
            int row = 16 * tiles[ti] + 4 * qd + reg;
            float* dst = out + ((size_t)b * T_DIM + row) * HEAD;
#pragma unroll
            for (int dn = 0; dn < 4; ++dn)
                dst[16 * dn + l15] = O[ti][dn][reg] * inv;
        }
    }
}

// ---------------------------------------------------------------------------
extern "C" void kernel_launch(void* const* d_in, const int* in_sizes, int n_in,
                              void* d_out, int out_size, void* d_ws, size_t ws_size,
                              hipStream_t stream) {
    const float* x  = (const float*)d_in[0];
    const float* Wq = (const float*)d_in[1];
    const float* Wk = (const float*)d_in[2];
    const float* Wv = (const float*)d_in[3];
    float* out = (float*)d_out;

    unsigned short* Wb = (unsigned short*)d_ws;   // 9216*8 bf16 = 147 KB

    wprep_kernel<<<36, 256, 0, stream>>>(Wq, Wk, Wv, Wb);
    fused_kernel<<<B_DIM, 512, 0, stream>>>(x, Wb, out);
}

// Round 3
// 173.818 us; speedup vs baseline: 1.0765x; 1.0765x over previous
//
#include <hip/hip_runtime.h>
#include <hip/hip_bf16.h>
#include <cstdint>
#include <cstddef>

#define B_DIM 256
#define T_DIM 256
#define EMB   384
#define HEAD  64

typedef __attribute__((ext_vector_type(8))) short bf16x8;
typedef __attribute__((ext_vector_type(4))) float f32x4;
typedef __attribute__((ext_vector_type(4))) unsigned int u32x4;

__device__ __forceinline__ unsigned short f2bf(float f) {
    union { float f; unsigned int u; } v; v.f = f;
    unsigned int r = v.u + 0x7fffu + ((v.u >> 16) & 1u);  // RNE
    return (unsigned short)(r >> 16);
}

__device__ __forceinline__ unsigned int pkbf(float a, float b) {
#if __has_builtin(__builtin_amdgcn_cvt_pk_bf16_f32)
    typedef __attribute__((ext_vector_type(2))) __bf16 bf16x2_t;
    bf16x2_t r = __builtin_amdgcn_cvt_pk_bf16_f32(a, b);
    return *(unsigned int*)&r;
#else
    return (unsigned)f2bf(a) | ((unsigned)f2bf(b) << 16);
#endif
}

// ---------------------------------------------------------------------------
// Kernel 0: W prep — Wq|Wk|Wv fp32 [384][64] -> Wb bf16, chunk-permuted for
// global_load_lds staging. Chunk g = kkstep*1536 + r*8 + cs holds the 8
// k-values of source chunk c = cs ^ (r&7) of output-col r in k-step kkstep.
// Makes the unpadded LDS image conflict-free for swizzled B-frag reads.
// ---------------------------------------------------------------------------
__global__ void wprep_kernel(const float* __restrict__ Wq, const float* __restrict__ Wk,
                             const float* __restrict__ Wv, unsigned short* __restrict__ Wb) {
    int g = blockIdx.x * blockDim.x + threadIdx.x;
    if (g >= 9216) return;                 // 6 k-steps * 1536 chunks
    int kkstep = g / 1536, rem = g - kkstep * 1536;
    int r = rem >> 3, cs = rem & 7, c = cs ^ (r & 7);
    const float* W = (r < 64) ? Wq : (r < 128) ? Wk : Wv;
    int h = r & 63;
    unsigned short tmp[8];
#pragma unroll
    for (int e = 0; e < 8; ++e) {
        int k = kkstep * 64 + c * 8 + e;
        tmp[e] = f2bf(W[k * HEAD + h]);
    }
    *(u32x4*)(Wb + (size_t)g * 8) = *(u32x4*)tmp;
}

// ---------------------------------------------------------------------------
// Fused kernel: one block per batch, 512 threads (8 waves), 1 block/CU.
//
// v4 (LDS x-stash, M-split): v2/v3's register stash was refused by the
// allocator (VGPR_Count pinned at 128 under both launch_bounds settings ->
// ~21 u32/thread spilled; plus the row-per-thread load shape made every
// load instr a 64-line gather -> 1.1 TB/s stream). v4 keeps the
// page-locality goal but stashes in LDS and keeps v1's proven coalesced
// load shape:
//   - Phase 1 splits M into two 128-token phases. Per phase, a prologue
//     reads those rows of x COMPLETELY: thread (trow=tid>>4, fc=tid&15)
//     loads 6 consecutive float4 walking one row's full 1536 B (per instr:
//     16 lanes x 16 B contiguous = 256 B; consecutive instrs revisit the
//     same rows at +256 B -> DRAM-page friendly), converts to bf16, and
//     ds_write_b64s into Xst[6][128][64] with XOR-chunk swizzle
//     (chunk' = chunk ^ (row&7); write pattern covers all 32 banks
//     exactly 4x per wave-instr = conflict-free; read pattern identical
//     in form to the proven Ws path).
//   - LDS: Xst 98,304 B + Ws[2] 49,152 B = 147,456 B (<160 KiB, 1 blk/CU).
//   - Waves retile to 2x4 (wm=w>>2, wn=w&3): 64 rows x 48 cols per wave,
//     acc[2][4][3] (96 regs) held across both phases; scatter to q/k/vT
//     once after phase B. Same 288 MFMA/wave total as v1.
//   - x is read ONCE, fp32, coalesced, page-local. No register stash ->
//     peak arch VGPR ~80, no spills.
// Phase 2 (attention) unchanged from v1: wave w owns row-tiles {w, 15-w};
// 17 col-tiles and 5 PV chunks per wave — balanced causal triangle.
// ---------------------------------------------------------------------------
__global__ __launch_bounds__(512, 1) void fused_kernel(const float* __restrict__ x,
                                                       const unsigned short* __restrict__ Wb,
                                                       float* __restrict__ out) {
    __shared__ union SM {
        struct { unsigned short Xst[6][128][64]; unsigned short Ws[2][12288]; } p1;  // 147,456 B
        struct { unsigned short qs[256][72]; unsigned short ks[256][72];
                 unsigned short vT[64][264]; unsigned short Ps[8][16][72]; } p2;     // 125,952 B
    } sm;

    const int tid = threadIdx.x;
    const int w = tid >> 6, lane = tid & 63, qd = lane >> 4, l15 = lane & 15;
    const int wm = w >> 2, wn = w & 3;            // 2x4 wave grid: 64 x 48 tile
    const int b = blockIdx.x;
    const float* xb = x + (size_t)b * T_DIM * EMB;
    const int trow = tid >> 4, fc = tid & 15;     // x-load coords: 32 rows x 16 float4

    // W glds: stage k-step KSTEP into Ws[BUF] (wave-uniform LDS base)
#define WGLDS(KSTEP, BUF) do { \
    _Pragma("unroll") \
    for (int s = 0; s < 3; ++s) { \
        int idx = s * 512 + w * 64; \
        const unsigned short* gp = Wb + (size_t)((KSTEP) * 1536 + idx + lane) * 8; \
        unsigned short* lp = &sm.p1.Ws[BUF][idx * 8]; \
        __builtin_amdgcn_global_load_lds( \
            (const __attribute__((address_space(1))) unsigned int*)gp, \
            (__attribute__((address_space(3))) unsigned int*)lp, 16, 0, 0); \
    } \
} while (0)

    // x loads for row-group RG of phase P: 6 float4 walking the row
#define XLOAD(P, RG) do { \
    _Pragma("unroll") \
    for (int kk = 0; kk < 6; ++kk) \
        xq[(RG) & 1][kk] = *(const float4*)(xb + (size_t)((P) * 128 + (RG) * 32 + trow) * EMB + kk * 64 + 4 * fc); \
} while (0)

    // convert + swizzled stash write for row-group RG (phase-local rows)
#define XCW(RG) do { \
    int row_ = (RG) * 32 + trow; \
    _Pragma("unroll") \
    for (int kk = 0; kk < 6; ++kk) { \
        float4 v_ = xq[(RG) & 1][kk]; \
        *(uint2*)((char*)&sm.p1.Xst[kk][row_][0] + ((((fc >> 1) ^ (row_ & 7)) << 4) | ((fc & 1) << 3))) = \
            make_uint2(pkbf(v_.x, v_.y), pkbf(v_.z, v_.w)); \
    } \
} while (0)

    f32x4 acc[2][4][3];
#pragma unroll
    for (int P = 0; P < 2; ++P)
#pragma unroll
        for (int mt = 0; mt < 4; ++mt)
#pragma unroll
            for (int nt = 0; nt < 3; ++nt) acc[P][mt][nt] = (f32x4){0.f, 0.f, 0.f, 0.f};

    float4 xq[2][6];

#pragma unroll
    for (int P = 0; P < 2; ++P) {
        // ---- phase prologue: W(0) glds + full x stream for these 128 rows ----
        WGLDS(0, 0);
        XLOAD(P, 0); XLOAD(P, 1);
        XCW(0);
        XLOAD(P, 2);
        XCW(1);
        XLOAD(P, 3);
        XCW(2);
        XCW(3);

        // ---- 6 k-steps: Ws double-buffered glds, Xst read in place ----
#pragma unroll
        for (int kk = 0; kk < 6; ++kk) {
            __syncthreads();   // drains prologue/prev glds (vmcnt) + LDS writes (lgkm)
            if (kk < 5) WGLDS(kk + 1, (kk + 1) & 1);
#pragma unroll
            for (int kb = 0; kb < 2; ++kb) {
                bf16x8 a[4], bb[3];
#pragma unroll
                for (int mt = 0; mt < 4; ++mt) {
                    int rl = 64 * wm + 16 * mt + l15;
                    a[mt] = *(const bf16x8*)((const char*)&sm.p1.Xst[kk][rl][0] +
                                             ((((kb << 2) + qd) ^ (rl & 7)) << 4));
                }
#pragma unroll
                for (int nt = 0; nt < 3; ++nt) {
                    int n = 48 * wn + 16 * nt + l15;
                    bb[nt] = *(const bf16x8*)&sm.p1.Ws[kk & 1][n * 64 + (((4 * kb + qd) ^ (n & 7)) << 3)];
                }
#pragma unroll
                for (int mt = 0; mt < 4; ++mt)
#pragma unroll
                    for (int nt = 0; nt < 3; ++nt)
                        acc[P][mt][nt] = __builtin_amdgcn_mfma_f32_16x16x32_bf16(a[mt], bb[nt], acc[P][mt][nt], 0, 0, 0);
            }
        }
        __syncthreads();       // all Xst/Ws reads done; next phase may overwrite
    }

    // scatter acc -> qs / ks / vT  (C/D layout: col=l15(ch), row=4*qd+reg(tok))
#pragma unroll
    for (int P = 0; P < 2; ++P)
#pragma unroll
        for (int nt = 0; nt < 3; ++nt) {
            int n = 48 * wn + 16 * nt + l15;
            int arr = n >> 6, hh = n & 63;     // wave-uniform per (wn,nt)
            if (arr == 2) {                    // vT: token-contiguous -> packed b64
#pragma unroll
                for (int mt = 0; mt < 4; ++mt) {
                    int tok0 = 128 * P + 64 * wm + 16 * mt + 4 * qd;
                    *(uint2*)&sm.p2.vT[hh][tok0] = make_uint2(
                        pkbf(acc[P][mt][nt][0], acc[P][mt][nt][1]),
                        pkbf(acc[P][mt][nt][2], acc[P][mt][nt][3]));
                }
            } else {
#pragma unroll
                for (int mt = 0; mt < 4; ++mt)
#pragma unroll
                    for (int reg = 0; reg < 4; ++reg) {
                        int tok = 128 * P + 64 * wm + 16 * mt + 4 * qd + reg;
                        unsigned short val = f2bf(acc[P][mt][nt][reg]);
                        if (arr == 0) sm.p2.qs[tok][hh] = val;
                        else          sm.p2.ks[tok][hh] = val;
                    }
            }
        }
    __syncthreads();       // q/k/vT ready

    // ---------------- attention, fully in LDS (unchanged) ----------------
    const int tiles[2] = { w, 15 - w };
    bf16x8 aq[2][2];
#pragma unroll
    for (int ti = 0; ti < 2; ++ti)
#pragma unroll
        for (int kbi = 0; kbi < 2; ++kbi)
            aq[ti][kbi] = *(const bf16x8*)&sm.p2.qs[16 * tiles[ti] + l15][32 * kbi + 8 * qd];

    f32x4 O[2][4];
    float l[2][4];
#pragma unroll
    for (int ti = 0; ti < 2; ++ti) {
#pragma unroll
        for (int dn = 0; dn < 4; ++dn) O[ti][dn] = (f32x4){0.f, 0.f, 0.f, 0.f};
#pragma unroll
        for (int reg = 0; reg < 4; ++reg) l[ti][reg] = 0.f;
    }

    const float cExp = 1.4426950408889634f / 19.595917942265423f; // log2(e)/sqrt(384)

#pragma unroll
    for (int ti = 0; ti < 2; ++ti) {
        const int t = tiles[ti];
        for (int jc = 0; jc <= (t >> 2); ++jc) {
            const int ntmax = min(3, t - 4 * jc);
            f32x4 S[4];
#pragma unroll
            for (int nt = 0; nt < 4; ++nt) {
                if (nt <= ntmax) {
                    bf16x8 b0 = *(const bf16x8*)&sm.p2.ks[64 * jc + 16 * nt + l15][8 * qd];
                    bf16x8 b1 = *(const bf16x8*)&sm.p2.ks[64 * jc + 16 * nt + l15][32 + 8 * qd];
                    f32x4 s = __builtin_amdgcn_mfma_f32_16x16x32_bf16(aq[ti][0], b0, (f32x4){0.f,0.f,0.f,0.f}, 0, 0, 0);
                    s = __builtin_amdgcn_mfma_f32_16x16x32_bf16(aq[ti][1], b1, s, 0, 0, 0);
                    S[nt] = s;
                }
            }
#pragma unroll
            for (int nt = 0; nt < 4; ++nt) {
#pragma unroll
                for (int reg = 0; reg < 4; ++reg) {
                    float p = 0.0f;
                    if (nt <= ntmax) {
                        p = exp2f(S[nt][reg] * cExp);
                        if (4 * jc + nt == t && (l15 > 4 * qd + reg)) p = 0.0f;  // diagonal mask
                    }
                    l[ti][reg] += p;
                    sm.p2.Ps[w][4 * qd + reg][16 * nt + l15] = f2bf(p);
                }
            }
            // C-layout -> A-layout via wave-private strip (no barrier needed)
            bf16x8 ap0 = *(const bf16x8*)&sm.p2.Ps[w][l15][8 * qd];
            bf16x8 ap1 = *(const bf16x8*)&sm.p2.Ps[w][l15][32 + 8 * qd];
#pragma unroll
            for (int dn = 0; dn < 4; ++dn) {
                bf16x8 bv0 = *(const bf16x8*)&sm.p2.vT[16 * dn + l15][64 * jc + 8 * qd];
                bf16x8 bv1 = *(const bf16x8*)&sm.p2.vT[16 * dn + l15][64 * jc + 32 + 8 * qd];
                O[ti][dn] = __builtin_amdgcn_mfma_f32_16x16x32_bf16(ap0, bv0, O[ti][dn], 0, 0, 0);
                O[ti][dn] = __builtin_amdgcn_mfma_f32_16x16x32_bf16(ap1, bv1, O[ti][dn], 0, 0, 0);
            }
        }
    }

#pragma unroll
    for (int ti = 0; ti < 2; ++ti) {
#pragma unroll
        for (int reg = 0; reg < 4; ++reg) {
            float s = l[ti][reg];
            s += __shfl_xor(s, 1);
            s += __shfl_xor(s, 2);
            s += __shfl_xor(s, 4);
            s += __shfl_xor(s, 8);
            float inv = 1.0f / s;
            int row = 16 * tiles[ti] + 4 * qd + reg;
            float* dst = out + ((size_t)b * T_DIM + row) * HEAD;
#pragma unroll
            for (int dn = 0; dn < 4; ++dn)
                dst[16 * dn + l15] = O[ti][dn][reg] * inv;
        }
    }
}

// ---------------------------------------------------------------------------
extern "C" void kernel_launch(void* const* d_in, const int* in_sizes, int n_in,
                              void* d_out, int out_size, void* d_ws, size_t ws_size,
                              hipStream_t stream) {
    const float* x  = (const float*)d_in[0];
    const float* Wq = (const float*)d_in[1];
    const float* Wk = (const float*)d_in[2];
    const float* Wv = (const float*)d_in[3];
    float* out = (float*)d_out;

    unsigned short* Wb = (unsigned short*)d_ws;   // 9216*8 bf16 = 147 KB

    wprep_kernel<<<36, 256, 0, stream>>>(Wq, Wk, Wv, Wb);
    fused_kernel<<<B_DIM, 512, 0, stream>>>(x, Wb, out);
}